// Round 13
// baseline (185.797 us; speedup 1.0000x reference)
//
#include <hip/hip_runtime.h>
#include <stdint.h>

// MatrixKAN as dense bf16 MFMA GEMM over expanded interpolation basis.
// Per feature slots [0..20]=hat (2 nonzero), 21=silu(xc) (pairs base_w), 22..23=pad.
// K = 512*24 = 12288. Plane-major A tiles in LDS; B fragments load directly from
// global Wt (R11: slab layout == frag layout, L2-served). KSPLIT=3: 768 blocks =
// 3/CU packed. bf16 split-K partials.
// R13: DOUBLE-BUFFERED A tile (2x24KB) + single barrier per iteration. R12 showed
// MFMA (2794 cyc) and LDS frag reads (~2400 cyc) fully serialized by the 2-barrier
// phase lock (wall 5157 cyc/iter = sum). Now: compute(buf[kt&1]) -> reload bv=
// B(kt+1) into same regs (in flight across barrier) -> stage kt+1 into other
// buffer (incremental, per-buffer clear caches) -> P(kt+2) -> one __syncthreads.
// No global_load_lds => barrier needs no vmcnt drain. No fences (R7), no NT (R5).

typedef short v8s __attribute__((ext_vector_type(8)));
typedef float v4f __attribute__((ext_vector_type(4)));

#define B_DIM 8192
#define IN_DIM 512
#define OUT_DIM 512
#define G_DIM 20
#define FPT 4                        // features per K-tile
#define KT_TOTAL (IN_DIM / FPT)      // 128 K-tiles
#define KSPLIT 3
#define BM 128
#define BN 128
#define CHUNKS 12                    // 16B chunks per tile-row (3 per feature)
#define PLANE 2048                   // 128 rows * 16B per chunk-plane
#define TILE_BYTES (CHUNKS * PLANE)  // 24 KB

#define P_BYTES ((size_t)IN_DIM * B_DIM * 8)                          // 33.55 MB
#define WT_BYTES ((size_t)(OUT_DIM / BN) * KT_TOTAL * TILE_BYTES)     // 12.58 MB
#define PART_ELEMS ((size_t)B_DIM * OUT_DIM)
#define WS_NEED (P_BYTES + WT_BYTES + (size_t)KSPLIT * PART_ELEMS * 2)

#define PACK_BLKS ((B_DIM / 64) * (IN_DIM / 64))   // 1024
#define WPACK_BLKS ((OUT_DIM * IN_DIM) / 256)      // 1024

static __device__ __forceinline__ unsigned f2bf(float f) {
  unsigned u = __builtin_bit_cast(unsigned, f);
  return (u + 0x7fffu + ((u >> 16) & 1u)) >> 16;   // RNE bf16
}

static __device__ __forceinline__ float bflo(unsigned u) {   // bf16 in low 16
  return __builtin_bit_cast(float, u << 16);
}
static __device__ __forceinline__ float bfhi(unsigned u) {   // bf16 in high 16
  return __builtin_bit_cast(float, u & 0xffff0000u);
}

__global__ void zero_out_kernel(uint4* __restrict__ out) {
  out[(size_t)blockIdx.x * 256 + threadIdx.x] = uint4{0u, 0u, 0u, 0u};
}

// Fused input-pack. Blocks [0, PACK_BLKS): x[b][i] -> P[i][b] packed
// {.x = bf16(1-t)|bf16(t)<<16, .y = idx|bf16(silu)<<16} via LDS transpose.
// Blocks [PACK_BLKS, +WPACK_BLKS): coeffs/base_w -> Wt plane-major 24KB slabs
// (slab (n_blk,kt): plane 3f+cf = slots 8cf..8cf+7 of feature kt*4+f, row=o&127).
__global__ void pack_fused_kernel(const float* __restrict__ x, uint2* __restrict__ P,
                                  const float* __restrict__ coeffs,
                                  const float* __restrict__ base_w,
                                  char* __restrict__ Wt) {
  __shared__ uint2 tile[64 * 65];
  const int t = threadIdx.x;
  if (blockIdx.x < PACK_BLKS) {
    const int b0 = (blockIdx.x & (B_DIM / 64 - 1)) * 64;
    const int i0 = (blockIdx.x / (B_DIM / 64)) * 64;
    const int tr = t >> 6;
    const int tc = t & 63;
#pragma unroll
    for (int it = 0; it < 16; ++it) {
      int br = it * 4 + tr;
      float xv = x[(size_t)(b0 + br) * IN_DIM + i0 + tc];
      float xc = fminf(fmaxf(xv, -1.0f), 1.0f);
      float xg = (xc + 1.0f) * 10.0f;           // (xc+1)*0.5*G
      int idx = (int)floorf(xg);
      idx = idx < 0 ? 0 : (idx > G_DIM - 1 ? G_DIM - 1 : idx);
      float tt = xg - (float)idx;
      float sl = xc / (1.0f + __expf(-xc));     // silu(clipped x)
      uint2 pv;
      pv.x = f2bf(1.0f - tt) | (f2bf(tt) << 16);
      pv.y = (unsigned)idx | (f2bf(sl) << 16);
      tile[tc * 65 + br] = pv;
    }
    __syncthreads();
#pragma unroll
    for (int it = 0; it < 16; ++it) {
      int ir = it * 4 + tr;
      P[(size_t)(i0 + ir) * B_DIM + b0 + tc] = tile[ir * 65 + tc];
    }
  } else {
    const unsigned u = (blockIdx.x - PACK_BLKS) * 256 + t;
    const int s = u >> 9;            // slab = n_blk*KT_TOTAL + kt
    const int w = u & 511;
    const int row = w >> 2;          // o & 127
    const int f = w & 3;
    const int n_blk = s / KT_TOTAL;
    const int kt = s - n_blk * KT_TOTAL;
    const int o = n_blk * 128 + row;
    const int i = kt * 4 + f;
    const size_t g = (size_t)o * IN_DIM + i;
    const float* c = coeffs + g * 21;
    float cf[21];
#pragma unroll
    for (int j = 0; j < 21; ++j) cf[j] = c[j];
    float bw = base_w[g];
    unsigned d[12];
#pragma unroll
    for (int j = 0; j < 10; ++j) d[j] = f2bf(cf[2 * j]) | (f2bf(cf[2 * j + 1]) << 16);
    d[10] = f2bf(cf[20]) | (f2bf(bw) << 16);  // slots 20, 21(=base_w)
    d[11] = 0u;                               // slots 22,23 pad
    char* slab = Wt + (size_t)s * TILE_BYTES;
#pragma unroll
    for (int p = 0; p < 3; ++p)
      *(uint4*)(slab + (3 * f + p) * PLANE + row * 16) =
          uint4{d[4 * p], d[4 * p + 1], d[4 * p + 2], d[4 * p + 3]};
  }
}

// out = p0+p1+p2: bf16 partial streams (8 per uint4), fp32 accumulate + store.
__global__ void reduce_kernel(const uint4* __restrict__ p, v4f* __restrict__ out) {
  size_t i = (size_t)blockIdx.x * 256 + threadIdx.x;
  const size_t q = PART_ELEMS / 8;
  uint4 a = p[i], b = p[i + q], c = p[i + 2 * q];
  v4f lo, hi;
  lo[0] = bflo(a.x) + bflo(b.x) + bflo(c.x);
  hi[0] = bfhi(a.x) + bfhi(b.x) + bfhi(c.x);
  lo[1] = bflo(a.y) + bflo(b.y) + bflo(c.y);
  hi[1] = bfhi(a.y) + bfhi(b.y) + bfhi(c.y);
  lo[2] = bflo(a.z) + bflo(b.z) + bflo(c.z);
  hi[2] = bfhi(a.z) + bfhi(b.z) + bfhi(c.z);
  lo[3] = bflo(a.w) + bflo(b.w) + bflo(c.w);
  hi[3] = bfhi(a.w) + bfhi(b.w) + bfhi(c.w);
  v4f o0 = {lo[0], hi[0], lo[1], hi[1]};
  v4f o1 = {lo[2], hi[2], lo[3], hi[3]};
  out[2 * i] = o0;
  out[2 * i + 1] = o1;
}

// slot -> byte offset within a lane's row slice (plane-major)
static __device__ __forceinline__ int slot_off(int slot) {
  return ((slot >> 3) << 11) + ((slot & 7) << 1);   // plane*2048 + within-chunk
}

// Incremental strip stage: clear previous hat slots (cached addrs), write new
// w0@idx, w1@idx+1, silu@21; update the cache.
static __device__ __forceinline__ void stage_inc(char* abase, uint2 pv,
                                                 char*& ca, char*& cb) {
  *(unsigned short*)ca = 0;
  *(unsigned short*)cb = 0;
  const int idx = (int)(pv.y & 0xffffu);
  char* wa = abase + slot_off(idx);
  char* wb = abase + slot_off(idx + 1);
  *(unsigned short*)wa = (unsigned short)pv.x;
  *(unsigned short*)wb = (unsigned short)(pv.x >> 16);
  *(unsigned short*)(abase + 2 * PLANE + 10) = (unsigned short)(pv.y >> 16);
  ca = wa;
  cb = wb;
}

template <bool ATOMIC>
__global__ __launch_bounds__(256, 3) void kan_gemm(const uint2* __restrict__ P,
                                                   const char* __restrict__ Wt,
                                                   unsigned short* __restrict__ part,
                                                   float* __restrict__ outA) {
  __shared__ uint4 lds4[2 * TILE_BYTES / 16];   // two 24KB A tiles (plane-major)
  const int t = threadIdx.x;
  const int lane = t & 63;
  const int wv = t >> 6;               // 4 waves, 2x2 grid of 64x64 tiles
  const int wm = wv >> 1, wn = wv & 1;
  const int b0 = blockIdx.x * BM;
  const int n_blk = blockIdx.y;
  const int z = blockIdx.z;
  const int kt0 = (z * KT_TOTAL) / KSPLIT;          // 0,42,85
  const int ktend = ((z + 1) * KT_TOTAL) / KSPLIT;  // 42,85,128

  v4f acc[4][4];
  const v4f z4 = {0.f, 0.f, 0.f, 0.f};
#pragma unroll
  for (int ii = 0; ii < 4; ++ii)
#pragma unroll
    for (int jj = 0; jj < 4; ++jj) acc[ii][jj] = z4;

  // zero both A buffers (3072 uint4 / 256 threads = 12 each)
  {
    const uint4 zz = {0u, 0u, 0u, 0u};
#pragma unroll
    for (int j = 0; j < 12; ++j) lds4[t + 256 * j] = zz;
  }
  __syncthreads();   // zero visible before cross-lane staging writes land

  // per-buffer strip bases: wave wv owns feature wv; lane owns rows lane, lane+64
  char* ab0[2];  // row = lane
  char* ab1[2];  // row = lane+64
#pragma unroll
  for (int p = 0; p < 2; ++p) {
    ab0[p] = (char*)lds4 + p * TILE_BYTES + 3 * wv * PLANE + lane * 16;
    ab1[p] = (char*)lds4 + p * TILE_BYTES + 3 * wv * PLANE + (lane + 64) * 16;
  }
  // per-buffer clear caches (init: slot 0 = no-op clear on zeroed buffer)
  char* c0a[2] = {ab0[0], ab0[1]};
  char* c0b[2] = {ab0[0] + 2, ab0[1] + 2};
  char* c1a[2] = {ab1[0], ab1[1]};
  char* c1b[2] = {ab1[0] + 2, ab1[1] + 2};

  // prologue: stage kt0 strips into buf[kt0&1]
  {
    const int p0 = kt0 & 1;
    uint2 s0 = P[(size_t)(kt0 * 4 + wv) * B_DIM + b0 + lane];
    uint2 s1 = P[(size_t)(kt0 * 4 + wv) * B_DIM + b0 + lane + 64];
    stage_inc(ab0[p0], s0, c0a[p0], c0b[p0]);
    stage_inc(ab1[p0], s1, c1a[p0], c1b[p0]);
  }
  // pv holds P(kt0+1) (staged during iter kt0)
  const int ktp = (kt0 + 1 < ktend) ? kt0 + 1 : ktend - 1;
  uint2 pv0 = P[(size_t)(ktp * 4 + wv) * B_DIM + b0 + lane];
  uint2 pv1 = P[(size_t)(ktp * 4 + wv) * B_DIM + b0 + lane + 64];

  const int r16 = lane & 15;
  const int q16 = lane >> 4;

  // B frag global addresses: uint4 index chunk*128 + row (row = wn*64+cn*16+r16)
  const uint4* wbase = (const uint4*)(Wt + (size_t)n_blk * KT_TOTAL * TILE_BYTES);
  int bidx[3][4];
#pragma unroll
  for (int s = 0; s < 3; ++s)
#pragma unroll
    for (int cn = 0; cn < 4; ++cn)
      bidx[s][cn] = (s * 4 + q16) * 128 + wn * 64 + cn * 16 + r16;

  // bv holds B(kt0)
  uint4 bv[3][4];
#pragma unroll
  for (int s = 0; s < 3; ++s)
#pragma unroll
    for (int cn = 0; cn < 4; ++cn)
      bv[s][cn] = wbase[(size_t)kt0 * (TILE_BYTES / 16) + bidx[s][cn]];

  __syncthreads();   // prologue staging visible

  for (int kt = kt0; kt < ktend; ++kt) {
    const char* cur = (const char*)lds4 + (kt & 1) * TILE_BYTES;
    const int pn = (kt + 1) & 1;

    // compute tile kt: A frags from cur, B from regs (loaded last iter)
#pragma unroll
    for (int s = 0; s < 3; ++s) {
      const int chunk = s * 4 + q16;   // plane index; k = chunk*8 + j
      v8s af[4];
#pragma unroll
      for (int rm = 0; rm < 4; ++rm) {
        int row = wm * 64 + rm * 16 + r16;
        af[rm] = *(const v8s*)(cur + chunk * PLANE + row * 16);
      }
#pragma unroll
      for (int rm = 0; rm < 4; ++rm)
#pragma unroll
        for (int cn = 0; cn < 4; ++cn)
          acc[rm][cn] = __builtin_amdgcn_mfma_f32_16x16x32_bf16(
              af[rm], __builtin_bit_cast(v8s, bv[s][cn]), acc[rm][cn], 0, 0, 0);
    }

    // prefetch B(kt+1) into the same regs -- in flight across the barrier
    const int ktn = (kt + 1 < ktend) ? kt + 1 : ktend - 1;
#pragma unroll
    for (int s = 0; s < 3; ++s)
#pragma unroll
      for (int cn = 0; cn < 4; ++cn)
        bv[s][cn] = wbase[(size_t)ktn * (TILE_BYTES / 16) + bidx[s][cn]];

    // stage strips for kt+1 into the other buffer (incremental)
    stage_inc(ab0[pn], pv0, c0a[pn], c0b[pn]);
    stage_inc(ab1[pn], pv1, c1a[pn], c1b[pn]);

    // prefetch P(kt+2)
    const int ktn2 = (kt + 2 < ktend) ? kt + 2 : ktend - 1;
    pv0 = P[(size_t)(ktn2 * 4 + wv) * B_DIM + b0 + lane];
    pv1 = P[(size_t)(ktn2 * 4 + wv) * B_DIM + b0 + lane + 64];

    __syncthreads();   // single barrier: staging of kt+1 visible for next iter
  }

  // epilogue: C/D layout col=lane&15, row=(lane>>4)*4+reg (verified m89/m91)
  const int q4 = (lane >> 4) * 4;
  if (ATOMIC) {
#pragma unroll
    for (int rm = 0; rm < 4; ++rm)
#pragma unroll
      for (int cn = 0; cn < 4; ++cn)
#pragma unroll
        for (int r = 0; r < 4; ++r) {
          int row = b0 + wm * 64 + rm * 16 + q4 + r;
          int col = n_blk * BN + wn * 64 + cn * 16 + r16;
          atomicAdd(outA + (size_t)row * OUT_DIM + col, acc[rm][cn][r]);
        }
  } else {
    // bf16 partials: half the split-K write traffic; reduce re-expands to fp32
    unsigned short* mypart = part + (size_t)z * PART_ELEMS;
#pragma unroll
    for (int rm = 0; rm < 4; ++rm)
#pragma unroll
      for (int cn = 0; cn < 4; ++cn)
#pragma unroll
        for (int r = 0; r < 4; ++r) {
          int row = b0 + wm * 64 + rm * 16 + q4 + r;
          int col = n_blk * BN + wn * 64 + cn * 16 + r16;
          mypart[(size_t)row * OUT_DIM + col] = (unsigned short)f2bf(acc[rm][cn][r]);
        }
  }
}

extern "C" void kernel_launch(void* const* d_in, const int* in_sizes, int n_in,
                              void* d_out, int out_size, void* d_ws, size_t ws_size,
                              hipStream_t stream) {
  const float* x = (const float*)d_in[0];
  const float* coeffs = (const float*)d_in[1];
  const float* base_w = (const float*)d_in[2];
  float* out = (float*)d_out;

  uint2* P = (uint2*)d_ws;
  char* Wt = (char*)d_ws + P_BYTES;
  unsigned short* part = (unsigned short*)((char*)d_ws + P_BYTES + WT_BYTES);

  pack_fused_kernel<<<PACK_BLKS + WPACK_BLKS, 256, 0, stream>>>(x, P, coeffs, base_w, Wt);

  if (ws_size >= WS_NEED) {
    kan_gemm<false><<<dim3(B_DIM / BM, OUT_DIM / BN, KSPLIT), 256, 0, stream>>>(P, Wt, part, out);
    reduce_kernel<<<(int)(PART_ELEMS / 8 / 256), 256, 0, stream>>>((const uint4*)part, (v4f*)out);
  } else {
    zero_out_kernel<<<(int)((PART_ELEMS * 4) / 4096), 256, 0, stream>>>((uint4*)out);
    kan_gemm<true><<<dim3(B_DIM / BM, OUT_DIM / BN, KSPLIT), 256, 0, stream>>>(P, Wt, part, out);
  }
}